// Round 1
// baseline (292.624 us; speedup 1.0000x reference)
//
#include <hip/hip_runtime.h>
#include <hip/hip_bf16.h>

typedef __attribute__((ext_vector_type(8))) short short8;
typedef __attribute__((ext_vector_type(4))) float floatx4;

#define B_SZ   64
#define N_TOK  32
#define S_TOK  1024
#define D_DIM  128
#define ALPHA  0.3f

__device__ __forceinline__ short f2bf(float f) {
    __hip_bfloat16 h = __float2bfloat16(f);
    return __builtin_bit_cast(short, h);
}

__device__ __forceinline__ short8 load_frag8(const float* __restrict__ p) {
    floatx4 f0 = *reinterpret_cast<const floatx4*>(p);
    floatx4 f1 = *reinterpret_cast<const floatx4*>(p + 4);
    short8 r;
    r[0] = f2bf(f0[0]); r[1] = f2bf(f0[1]); r[2] = f2bf(f0[2]); r[3] = f2bf(f0[3]);
    r[4] = f2bf(f1[0]); r[5] = f2bf(f1[1]); r[6] = f2bf(f1[2]); r[7] = f2bf(f1[3]);
    return r;
}

// Grid: (c = 64, bgroup = 32, which = 2), block = 256 threads (4 waves).
// Each block: scores[b0..b0+1][c] for one matrix (student/teacher).
__global__ __launch_bounds__(256) void maxsim_scores_kernel(
    const float* __restrict__ q,  const float* __restrict__ d,
    const float* __restrict__ tq, const float* __restrict__ td,
    float* __restrict__ scores_ws /* [2][64][64] */) {

    const int c     = blockIdx.x;
    const int bg    = blockIdx.y;
    const int which = blockIdx.z;
    const float* Q = which ? tq : q;
    const float* D = which ? td : d;
    float* out = scores_ws + which * (B_SZ * B_SZ);

    const int tid = threadIdx.x;
    const int w   = tid >> 6;     // wave 0..3
    const int l   = tid & 63;     // lane
    const int lg  = l >> 4;       // lane group 0..3
    const int lr  = l & 15;       // row/col within 16

    const int b0 = bg * 2;

    // Preload A fragments: mt in 0..3 maps to (b = b0 + mt/2, n = (mt&1)*16 + lr)
    short8 afrag[4][4];
#pragma unroll
    for (int mt = 0; mt < 4; ++mt) {
        const float* qrow = Q + (size_t)(b0 + (mt >> 1)) * N_TOK * D_DIM
                              + ((mt & 1) * 16 + lr) * D_DIM + lg * 8;
#pragma unroll
        for (int ks = 0; ks < 4; ++ks)
            afrag[mt][ks] = load_frag8(qrow + ks * 32);
    }

    float runmax[4][4];
#pragma unroll
    for (int mt = 0; mt < 4; ++mt)
#pragma unroll
        for (int j = 0; j < 4; ++j) runmax[mt][j] = -INFINITY;

    // B fragment: lane holds D[c][s = s_base + lr][k = ks*32 + lg*8 + 0..7]
    const float* drow_base = D + (size_t)c * S_TOK * D_DIM + (size_t)lr * D_DIM + lg * 8;

    for (int st = w; st < S_TOK / 16; st += 4) {
        const float* drow = drow_base + (size_t)st * 16 * D_DIM;
        short8 bfrag[4];
#pragma unroll
        for (int ks = 0; ks < 4; ++ks)
            bfrag[ks] = load_frag8(drow + ks * 32);
#pragma unroll
        for (int mt = 0; mt < 4; ++mt) {
            floatx4 acc = {0.f, 0.f, 0.f, 0.f};
#pragma unroll
            for (int ks = 0; ks < 4; ++ks)
                acc = __builtin_amdgcn_mfma_f32_16x16x32_bf16(afrag[mt][ks], bfrag[ks], acc, 0, 0, 0);
#pragma unroll
            for (int j = 0; j < 4; ++j)
                runmax[mt][j] = fmaxf(runmax[mt][j], acc[j]);
        }
    }

    // Max over the 16 columns held across lanes (same lane-group lg, varying lr).
#pragma unroll
    for (int mt = 0; mt < 4; ++mt)
#pragma unroll
        for (int j = 0; j < 4; ++j) {
            float v = runmax[mt][j];
            v = fmaxf(v, __shfl_xor(v, 1));
            v = fmaxf(v, __shfl_xor(v, 2));
            v = fmaxf(v, __shfl_xor(v, 4));
            v = fmaxf(v, __shfl_xor(v, 8));
            runmax[mt][j] = v;
        }

    // Combine partial maxima across the 4 waves (disjoint s ranges).
    __shared__ float lds_max[4][64];
    if (lr == 0) {
#pragma unroll
        for (int mt = 0; mt < 4; ++mt)
#pragma unroll
            for (int j = 0; j < 4; ++j)
                lds_max[w][mt * 16 + lg * 4 + j] = runmax[mt][j];
    }
    __syncthreads();

    if (tid < 64) {
        const int r = tid;  // global row m = 32*b_local + n
        float v = fmaxf(fmaxf(lds_max[0][r], lds_max[1][r]),
                        fmaxf(lds_max[2][r], lds_max[3][r]));
        // sum over n within each 32-lane half
#pragma unroll
        for (int m = 1; m < 32; m <<= 1) v += __shfl_xor(v, m);
        if ((tid & 31) == 0) {
            const int b = b0 + (tid >> 5);
            out[b * B_SZ + c] = v;
        }
    }
}

// 1 block, 64 threads: final loss.
__global__ void loss_kernel(const float* __restrict__ scores_ws, float* __restrict__ out) {
    const float* sc = scores_ws;                 // student [64][64]
    const float* tc = scores_ws + B_SZ * B_SZ;   // teacher [64][64]
    const int b = threadIdx.x;                   // 0..63

    float pos = sc[b * B_SZ + b];
    float neg = -INFINITY;
    float msesum = 0.f;
#pragma unroll 8
    for (int cc = 0; cc < B_SZ; ++cc) {
        float s = sc[b * B_SZ + cc];
        float t = tc[b * B_SZ + cc];
        if (cc != b) neg = fmaxf(neg, s);
        _Float16 d16 = (_Float16)s - (_Float16)t;  // fp16 subtract (matches ref cast)
        _Float16 sq  = d16 * d16;                  // fp16 square
        msesum += (float)sq;                       // fp32 accumulation (jnp/np f16-mean)
    }
    float x = neg - pos;
    float sp = (x > 0.f) ? (x + log1pf(expf(-x))) : log1pf(expf(x));

#pragma unroll
    for (int m = 1; m < 64; m <<= 1) {
        sp     += __shfl_xor(sp, m);
        msesum += __shfl_xor(msesum, m);
    }
    if (b == 0) {
        float mse = msesum / 4096.f;
        mse = (float)(_Float16)mse;  // jnp.mean returns f16, then astype(f32)
        out[0] = sp / 64.f + ALPHA * mse;
    }
}

extern "C" void kernel_launch(void* const* d_in, const int* in_sizes, int n_in,
                              void* d_out, int out_size, void* d_ws, size_t ws_size,
                              hipStream_t stream) {
    const float* q  = (const float*)d_in[0];
    const float* d  = (const float*)d_in[1];
    const float* tq = (const float*)d_in[2];
    const float* td = (const float*)d_in[3];
    float* scores_ws = (float*)d_ws;      // 2 * 64 * 64 floats = 32 KB
    float* out = (float*)d_out;

    dim3 grid(B_SZ, B_SZ / 2, 2);
    maxsim_scores_kernel<<<grid, 256, 0, stream>>>(q, d, tq, td, scores_ws);
    loss_kernel<<<1, 64, 0, stream>>>(scores_ws, out);
}

// Round 2
// 182.758 us; speedup vs baseline: 1.6012x; 1.6012x over previous
//
#include <hip/hip_runtime.h>
#include <hip/hip_bf16.h>

typedef __attribute__((ext_vector_type(8))) short short8;
typedef __attribute__((ext_vector_type(4))) float floatx4;

#define B_SZ   64
#define N_TOK  32
#define S_TOK  1024
#define D_DIM  128
#define ALPHA  0.3f

__device__ __forceinline__ short f2bf(float f) {
    __hip_bfloat16 h = __float2bfloat16(f);
    return __builtin_bit_cast(short, h);
}

// Convert 8 fp32 -> 8 bf16 per thread. n8 = n/8.
__global__ __launch_bounds__(256) void cvt_bf16_kernel(
    const float* __restrict__ src, __hip_bfloat16* __restrict__ dst, int n8) {
    int idx = blockIdx.x * 256 + threadIdx.x;
    if (idx >= n8) return;
    const float* p = src + (size_t)idx * 8;
    floatx4 f0 = *reinterpret_cast<const floatx4*>(p);
    floatx4 f1 = *reinterpret_cast<const floatx4*>(p + 4);
    short8 r;
    r[0] = f2bf(f0[0]); r[1] = f2bf(f0[1]); r[2] = f2bf(f0[2]); r[3] = f2bf(f0[3]);
    r[4] = f2bf(f1[0]); r[5] = f2bf(f1[1]); r[6] = f2bf(f1[2]); r[7] = f2bf(f1[3]);
    *reinterpret_cast<short8*>(dst + (size_t)idx * 8) = r;
}

// Grid: (c = 64, bgroup = 32, which = 2), block = 256 threads (4 waves).
// Each block computes scores[b0..b0+1][c] for one matrix (student/teacher).
// Inputs are pre-converted bf16.
__global__ __launch_bounds__(256) void maxsim_scores_kernel(
    const __hip_bfloat16* __restrict__ qb,  const __hip_bfloat16* __restrict__ db,
    const __hip_bfloat16* __restrict__ tqb, const __hip_bfloat16* __restrict__ tdb,
    float* __restrict__ scores_ws /* [2][64][64] */) {

    const int c     = blockIdx.x;
    const int bg    = blockIdx.y;
    const int which = blockIdx.z;
    const __hip_bfloat16* Q = which ? tqb : qb;
    const __hip_bfloat16* D = which ? tdb : db;
    float* out = scores_ws + which * (B_SZ * B_SZ);

    const int tid = threadIdx.x;
    const int w   = tid >> 6;     // wave 0..3
    const int l   = tid & 63;     // lane
    const int lg  = l >> 4;       // lane group 0..3
    const int lr  = l & 15;       // row/col within 16

    const int b0 = bg * 2;

    // Preload A fragments: mt in 0..3 -> (b = b0 + mt/2, n = (mt&1)*16 + lr)
    short8 afrag[4][4];
#pragma unroll
    for (int mt = 0; mt < 4; ++mt) {
        const __hip_bfloat16* qrow = Q + (size_t)(b0 + (mt >> 1)) * N_TOK * D_DIM
                                       + ((size_t)((mt & 1) * 16 + lr)) * D_DIM + lg * 8;
#pragma unroll
        for (int ks = 0; ks < 4; ++ks)
            afrag[mt][ks] = *reinterpret_cast<const short8*>(qrow + ks * 32);
    }

    float runmax[4][4];
#pragma unroll
    for (int mt = 0; mt < 4; ++mt)
#pragma unroll
        for (int j = 0; j < 4; ++j) runmax[mt][j] = -INFINITY;

    // B fragment: lane holds D[c][s = st*16 + lr][k = ks*32 + lg*8 + 0..7]
    const __hip_bfloat16* dbase = D + ((size_t)c * S_TOK + lr) * D_DIM + lg * 8;
    const size_t strip = (size_t)16 * D_DIM;  // elements per 16-row s-strip

    short8 bcur[4];
#pragma unroll
    for (int ks = 0; ks < 4; ++ks)
        bcur[ks] = *reinterpret_cast<const short8*>(dbase + (size_t)w * strip + ks * 32);

    for (int st = w; st < S_TOK / 16; st += 4) {
        // Prefetch next strip (redundant reload of current on the last iter).
        const int stn = (st + 4 < S_TOK / 16) ? st + 4 : st;
        short8 bnext[4];
#pragma unroll
        for (int ks = 0; ks < 4; ++ks)
            bnext[ks] = *reinterpret_cast<const short8*>(dbase + (size_t)stn * strip + ks * 32);

#pragma unroll
        for (int mt = 0; mt < 4; ++mt) {
            floatx4 acc = {0.f, 0.f, 0.f, 0.f};
#pragma unroll
            for (int ks = 0; ks < 4; ++ks)
                acc = __builtin_amdgcn_mfma_f32_16x16x32_bf16(afrag[mt][ks], bcur[ks], acc, 0, 0, 0);
#pragma unroll
            for (int j = 0; j < 4; ++j)
                runmax[mt][j] = fmaxf(runmax[mt][j], acc[j]);
        }
#pragma unroll
        for (int ks = 0; ks < 4; ++ks) bcur[ks] = bnext[ks];
    }

    // Max over the 16 columns held across lanes (same lane-group lg, varying lr).
#pragma unroll
    for (int mt = 0; mt < 4; ++mt)
#pragma unroll
        for (int j = 0; j < 4; ++j) {
            float v = runmax[mt][j];
            v = fmaxf(v, __shfl_xor(v, 1));
            v = fmaxf(v, __shfl_xor(v, 2));
            v = fmaxf(v, __shfl_xor(v, 4));
            v = fmaxf(v, __shfl_xor(v, 8));
            runmax[mt][j] = v;
        }

    // Combine partial maxima across the 4 waves (disjoint s ranges).
    __shared__ float lds_max[4][64];
    if (lr == 0) {
#pragma unroll
        for (int mt = 0; mt < 4; ++mt)
#pragma unroll
            for (int j = 0; j < 4; ++j)
                lds_max[w][mt * 16 + lg * 4 + j] = runmax[mt][j];
    }
    __syncthreads();

    if (tid < 64) {
        const int r = tid;  // row m = 32*b_local + n
        float v = fmaxf(fmaxf(lds_max[0][r], lds_max[1][r]),
                        fmaxf(lds_max[2][r], lds_max[3][r]));
#pragma unroll
        for (int m = 1; m < 32; m <<= 1) v += __shfl_xor(v, m);
        if ((tid & 31) == 0) {
            const int b = b0 + (tid >> 5);
            out[b * B_SZ + c] = v;
        }
    }
}

// 1 block, 64 threads: final loss.
__global__ void loss_kernel(const float* __restrict__ scores_ws, float* __restrict__ out) {
    const float* sc = scores_ws;                 // student [64][64]
    const float* tc = scores_ws + B_SZ * B_SZ;   // teacher [64][64]
    const int b = threadIdx.x;                   // 0..63

    float pos = sc[b * B_SZ + b];
    float neg = -INFINITY;
    float msesum = 0.f;
#pragma unroll 8
    for (int cc = 0; cc < B_SZ; ++cc) {
        float s = sc[b * B_SZ + cc];
        float t = tc[b * B_SZ + cc];
        if (cc != b) neg = fmaxf(neg, s);
        _Float16 d16 = (_Float16)s - (_Float16)t;  // fp16 subtract (matches ref cast)
        _Float16 sq  = d16 * d16;                  // fp16 square
        msesum += (float)sq;                       // fp32 accumulation
    }
    float x = neg - pos;
    float sp = (x > 0.f) ? (x + log1pf(expf(-x))) : log1pf(expf(x));

#pragma unroll
    for (int m = 1; m < 64; m <<= 1) {
        sp     += __shfl_xor(sp, m);
        msesum += __shfl_xor(msesum, m);
    }
    if (b == 0) {
        float mse = msesum / 4096.f;
        mse = (float)(_Float16)mse;  // jnp.mean returns f16, then astype(f32)
        out[0] = sp / 64.f + ALPHA * mse;
    }
}

extern "C" void kernel_launch(void* const* d_in, const int* in_sizes, int n_in,
                              void* d_out, int out_size, void* d_ws, size_t ws_size,
                              hipStream_t stream) {
    const float* q  = (const float*)d_in[0];
    const float* d  = (const float*)d_in[1];
    const float* tq = (const float*)d_in[2];
    const float* td = (const float*)d_in[3];
    float* out = (float*)d_out;

    const size_t QN = (size_t)B_SZ * N_TOK * D_DIM;   // 262144
    const size_t DN = (size_t)B_SZ * S_TOK * D_DIM;   // 8388608

    float* scores_ws = (float*)d_ws;                                  // 32 KB
    __hip_bfloat16* qb  = (__hip_bfloat16*)((char*)d_ws + 32768);
    __hip_bfloat16* tqb = qb + QN;
    __hip_bfloat16* db  = tqb + QN;
    __hip_bfloat16* tdb = db + DN;

    // fp32 -> bf16 pre-conversion (memory-bound, ~100 MB total traffic)
    cvt_bf16_kernel<<<(int)(QN / 8 / 256), 256, 0, stream>>>(q,  qb,  (int)(QN / 8));
    cvt_bf16_kernel<<<(int)(QN / 8 / 256), 256, 0, stream>>>(tq, tqb, (int)(QN / 8));
    cvt_bf16_kernel<<<(int)(DN / 8 / 256), 256, 0, stream>>>(d,  db,  (int)(DN / 8));
    cvt_bf16_kernel<<<(int)(DN / 8 / 256), 256, 0, stream>>>(td, tdb, (int)(DN / 8));

    dim3 grid(B_SZ, B_SZ / 2, 2);
    maxsim_scores_kernel<<<grid, 256, 0, stream>>>(qb, db, tqb, tdb, scores_ws);
    loss_kernel<<<1, 64, 0, stream>>>(scores_ws, out);
}

// Round 3
// 94.058 us; speedup vs baseline: 3.1111x; 1.9430x over previous
//
#include <hip/hip_runtime.h>
#include <hip/hip_bf16.h>

typedef __attribute__((ext_vector_type(8))) short short8;
typedef __attribute__((ext_vector_type(4))) float floatx4;

#define B_SZ   64
#define N_TOK  32
#define S_TOK  1024
#define D_DIM  128
#define ALPHA  0.3f

#define STRIP_S     32
#define STRIP_BYTES (STRIP_S * D_DIM * 2)   // 8192 B
#define NSTRIP      (S_TOK / STRIP_S)       // 32

__device__ __forceinline__ short f2bf(float f) {
    __hip_bfloat16 h = __float2bfloat16(f);
    return __builtin_bit_cast(short, h);
}

// Convert 8 fp32 -> 8 bf16 per thread. n8 = n/8.
__global__ __launch_bounds__(256) void cvt_bf16_kernel(
    const float* __restrict__ src, __hip_bfloat16* __restrict__ dst, int n8) {
    int idx = blockIdx.x * 256 + threadIdx.x;
    if (idx >= n8) return;
    const float* p = src + (size_t)idx * 8;
    floatx4 f0 = *reinterpret_cast<const floatx4*>(p);
    floatx4 f1 = *reinterpret_cast<const floatx4*>(p + 4);
    short8 r;
    r[0] = f2bf(f0[0]); r[1] = f2bf(f0[1]); r[2] = f2bf(f0[2]); r[3] = f2bf(f0[3]);
    r[4] = f2bf(f1[0]); r[5] = f2bf(f1[1]); r[6] = f2bf(f1[2]); r[7] = f2bf(f1[3]);
    *reinterpret_cast<short8*>(dst + (size_t)idx * 8) = r;
}

__device__ __forceinline__ void gload_lds16(const void* g, void* l) {
    __builtin_amdgcn_global_load_lds(
        (const __attribute__((address_space(1))) unsigned int*)g,
        (__attribute__((address_space(3))) unsigned int*)l, 16, 0, 0);
}

// XOR swizzle within an 8 KB strip: rows are 256 B; spread row r's 16B chunks
// across banks. Involution; preserves bits 0-3 (16B alignment) and bits >=7.
__device__ __forceinline__ unsigned swz(unsigned y) {
    return y ^ (((y >> 8) & 7) << 4);
}

// Grid: (c = 64, bg = 16, which = 2), block = 256 threads (4 waves).
// Wave w computes scores[bg*4 + w][c]. D[c] strips staged in LDS, dbuf.
__global__ __launch_bounds__(256) void maxsim_scores_kernel(
    const __hip_bfloat16* __restrict__ qb,  const __hip_bfloat16* __restrict__ db,
    const __hip_bfloat16* __restrict__ tqb, const __hip_bfloat16* __restrict__ tdb,
    float* __restrict__ scores_ws /* [2][64][64] */) {

    const int c     = blockIdx.x;
    const int bg    = blockIdx.y;
    const int which = blockIdx.z;
    const __hip_bfloat16* Q = which ? tqb : qb;
    const __hip_bfloat16* D = which ? tdb : db;
    float* out = scores_ws + which * (B_SZ * B_SZ);

    const int tid = threadIdx.x;
    const int w   = tid >> 6;     // wave 0..3
    const int l   = tid & 63;     // lane
    const int lg  = l >> 4;       // lane group 0..3 (k-subrange)
    const int lr  = l & 15;       // row/col within 16

    const int b = bg * 4 + w;     // batch owned by this wave

    __shared__ __align__(16) char smem[2 * STRIP_BYTES];  // 16 KB dbuf

    // A fragments: afrag[mt][ks] = Q[b][mt*16 + lr][ks*32 + lg*8 .. +7]
    short8 afrag[2][4];
#pragma unroll
    for (int mt = 0; mt < 2; ++mt)
#pragma unroll
        for (int ks = 0; ks < 4; ++ks)
            afrag[mt][ks] = *reinterpret_cast<const short8*>(
                Q + ((size_t)b * N_TOK + mt * 16 + lr) * D_DIM + ks * 32 + lg * 8);

    float runmax[2][4];
#pragma unroll
    for (int mt = 0; mt < 2; ++mt)
#pragma unroll
        for (int j = 0; j < 4; ++j) runmax[mt][j] = -INFINITY;

    const char* gstrip = (const char*)(D + (size_t)c * S_TOK * D_DIM);

    const unsigned y0 = tid * 16;          // first 4 KB half
    const unsigned y1 = 4096 + tid * 16;   // second 4 KB half

    // Prologue: stage strip 0 into buffer 0 (pre-swizzled global source).
    gload_lds16(gstrip + swz(y0), smem + y0);
    gload_lds16(gstrip + swz(y1), smem + y1);
    __syncthreads();

    for (int st = 0; st < NSTRIP; ++st) {
        char* bufc = smem + (size_t)(st & 1) * STRIP_BYTES;

        // Issue next strip's staging loads BEFORE computing current strip.
        if (st + 1 < NSTRIP) {
            const char* gs = gstrip + (size_t)(st + 1) * STRIP_BYTES;
            char* bufn = smem + (size_t)((st + 1) & 1) * STRIP_BYTES;
            gload_lds16(gs + swz(y0), bufn + y0);
            gload_lds16(gs + swz(y1), bufn + y1);
        }

        // B fragments from LDS (swizzled read): lane holds
        // Dstrip[s = nt*16 + lr][k = ks*32 + lg*8 .. +7]
        short8 bf[2][4];
#pragma unroll
        for (int nt = 0; nt < 2; ++nt)
#pragma unroll
            for (int ks = 0; ks < 4; ++ks) {
                unsigned a = (unsigned)((nt * 16 + lr) * 256 + ks * 64 + lg * 16);
                a ^= ((unsigned)(lr & 7)) << 4;
                bf[nt][ks] = *reinterpret_cast<const short8*>(bufc + a);
            }

        floatx4 acc[2][2];
#pragma unroll
        for (int mt = 0; mt < 2; ++mt)
#pragma unroll
            for (int nt = 0; nt < 2; ++nt)
                acc[mt][nt] = floatx4{0.f, 0.f, 0.f, 0.f};

#pragma unroll
        for (int ks = 0; ks < 4; ++ks)
#pragma unroll
            for (int mt = 0; mt < 2; ++mt)
#pragma unroll
                for (int nt = 0; nt < 2; ++nt)
                    acc[mt][nt] = __builtin_amdgcn_mfma_f32_16x16x32_bf16(
                        afrag[mt][ks], bf[nt][ks], acc[mt][nt], 0, 0, 0);

#pragma unroll
        for (int mt = 0; mt < 2; ++mt)
#pragma unroll
            for (int j = 0; j < 4; ++j)
                runmax[mt][j] = fmaxf(fmaxf(runmax[mt][j], acc[mt][0][j]), acc[mt][1][j]);

        __syncthreads();  // drains staging vmcnt + protects dbuf reuse
    }

    // Per-wave reduction. runmax[mt][j] covers row m = mt*16 + lg*4 + j,
    // col = lr-th s within tiles. Max over the 16 cols spread across lr:
#pragma unroll
    for (int mt = 0; mt < 2; ++mt)
#pragma unroll
        for (int j = 0; j < 4; ++j) {
            float v = runmax[mt][j];
            v = fmaxf(v, __shfl_xor(v, 1));
            v = fmaxf(v, __shfl_xor(v, 2));
            v = fmaxf(v, __shfl_xor(v, 4));
            v = fmaxf(v, __shfl_xor(v, 8));
            runmax[mt][j] = v;
        }

    // Sum over the 32 rows of this wave's batch: 8 rows per lane (mt,j at
    // fixed lg), then combine the 4 lane-groups.
    float s = 0.f;
#pragma unroll
    for (int mt = 0; mt < 2; ++mt)
#pragma unroll
        for (int j = 0; j < 4; ++j) s += runmax[mt][j];
    s += __shfl_xor(s, 16);
    s += __shfl_xor(s, 32);

    if (l == 0) out[b * B_SZ + c] = s;
}

// 1 block, 64 threads: final loss.
__global__ void loss_kernel(const float* __restrict__ scores_ws, float* __restrict__ out) {
    const float* sc = scores_ws;                 // student [64][64]
    const float* tc = scores_ws + B_SZ * B_SZ;   // teacher [64][64]
    const int b = threadIdx.x;                   // 0..63

    float pos = sc[b * B_SZ + b];
    float neg = -INFINITY;
    float msesum = 0.f;
#pragma unroll 8
    for (int cc = 0; cc < B_SZ; ++cc) {
        float s = sc[b * B_SZ + cc];
        float t = tc[b * B_SZ + cc];
        if (cc != b) neg = fmaxf(neg, s);
        _Float16 d16 = (_Float16)s - (_Float16)t;  // fp16 subtract (matches ref cast)
        _Float16 sq  = d16 * d16;                  // fp16 square
        msesum += (float)sq;                       // fp32 accumulation
    }
    float x = neg - pos;
    float sp = (x > 0.f) ? (x + log1pf(expf(-x))) : log1pf(expf(x));

#pragma unroll
    for (int m = 1; m < 64; m <<= 1) {
        sp     += __shfl_xor(sp, m);
        msesum += __shfl_xor(msesum, m);
    }
    if (b == 0) {
        float mse = msesum / 4096.f;
        mse = (float)(_Float16)mse;  // jnp.mean returns f16, then astype(f32)
        out[0] = sp / 64.f + ALPHA * mse;
    }
}

extern "C" void kernel_launch(void* const* d_in, const int* in_sizes, int n_in,
                              void* d_out, int out_size, void* d_ws, size_t ws_size,
                              hipStream_t stream) {
    const float* q  = (const float*)d_in[0];
    const float* d  = (const float*)d_in[1];
    const float* tq = (const float*)d_in[2];
    const float* td = (const float*)d_in[3];
    float* out = (float*)d_out;

    const size_t QN = (size_t)B_SZ * N_TOK * D_DIM;   // 262144
    const size_t DN = (size_t)B_SZ * S_TOK * D_DIM;   // 8388608

    float* scores_ws = (float*)d_ws;                                  // 32 KB
    __hip_bfloat16* qb  = (__hip_bfloat16*)((char*)d_ws + 32768);
    __hip_bfloat16* tqb = qb + QN;
    __hip_bfloat16* db  = tqb + QN;
    __hip_bfloat16* tdb = db + DN;

    // fp32 -> bf16 pre-conversion (memory-bound, ~100 MB total traffic)
    cvt_bf16_kernel<<<(int)(QN / 8 / 256), 256, 0, stream>>>(q,  qb,  (int)(QN / 8));
    cvt_bf16_kernel<<<(int)(QN / 8 / 256), 256, 0, stream>>>(tq, tqb, (int)(QN / 8));
    cvt_bf16_kernel<<<(int)(DN / 8 / 256), 256, 0, stream>>>(d,  db,  (int)(DN / 8));
    cvt_bf16_kernel<<<(int)(DN / 8 / 256), 256, 0, stream>>>(td, tdb, (int)(DN / 8));

    dim3 grid(B_SZ, B_SZ / 4, 2);
    maxsim_scores_kernel<<<grid, 256, 0, stream>>>(qb, db, tqb, tdb, scores_ws);
    loss_kernel<<<1, 64, 0, stream>>>(scores_ws, out);
}

// Round 4
// 80.166 us; speedup vs baseline: 3.6502x; 1.1733x over previous
//
#include <hip/hip_runtime.h>
#include <hip/hip_bf16.h>

typedef __attribute__((ext_vector_type(8))) short short8;
typedef __attribute__((ext_vector_type(4))) float floatx4;

#define B_SZ   64
#define N_TOK  32
#define S_TOK  1024
#define D_DIM  128
#define ALPHA  0.3f

#define STRIP_S     32
#define STRIP_EL    (STRIP_S * D_DIM)       // 4096 elements
#define STRIP_BYTES (STRIP_EL * 2)          // 8192 B
#define NSTRIP      (S_TOK / STRIP_S)       // 32
#define C_EL        (S_TOK * D_DIM)         // 131072 elements per doc batch

__device__ __forceinline__ short f2bf(float f) {
    __hip_bfloat16 h = __float2bfloat16(f);
    return __builtin_bit_cast(short, h);
}

__device__ __forceinline__ short8 cvt8(const float* __restrict__ p) {
    floatx4 f0 = *reinterpret_cast<const floatx4*>(p);
    floatx4 f1 = *reinterpret_cast<const floatx4*>(p + 4);
    short8 r;
    r[0] = f2bf(f0[0]); r[1] = f2bf(f0[1]); r[2] = f2bf(f0[2]); r[3] = f2bf(f0[3]);
    r[4] = f2bf(f1[0]); r[5] = f2bf(f1[1]); r[6] = f2bf(f1[2]); r[7] = f2bf(f1[3]);
    return r;
}

// Q: plain fp32 -> bf16, layout unchanged. grid (QN/8/256, 2).
__global__ __launch_bounds__(256) void cvt_q_kernel(
    const float* __restrict__ q, const float* __restrict__ tq,
    __hip_bfloat16* __restrict__ qb, __hip_bfloat16* __restrict__ tqb) {
    const float* src = blockIdx.y ? tq : q;
    __hip_bfloat16* dst = blockIdx.y ? tqb : qb;
    int idx = blockIdx.x * 256 + threadIdx.x;
    *reinterpret_cast<short8*>(dst + (size_t)idx * 8) = cvt8(src + (size_t)idx * 8);
}

// D: fp32 -> bf16 with fragment permutation. grid (DN/8/256, 2).
// dst element pos = c*C_EL + st*STRIP_EL + (ks*2+nt)*512 + (lg*16+lr)*8 + e
// where s = st*32 + nt*16 + lr, k = ks*32 + lg*8 + e.
__global__ __launch_bounds__(256) void cvt_d_kernel(
    const float* __restrict__ d, const float* __restrict__ td,
    __hip_bfloat16* __restrict__ db, __hip_bfloat16* __restrict__ tdb) {
    const float* src = blockIdx.y ? td : d;
    __hip_bfloat16* dst = blockIdx.y ? tdb : db;
    int idx = blockIdx.x * 256 + threadIdx.x;
    int kc = idx & 15;            // k-chunk 0..15
    int s  = (idx >> 4) & (S_TOK - 1);
    int c  = idx >> 14;
    int st = s >> 5, nt = (s >> 4) & 1, lr = s & 15;
    int ks = kc >> 2, lg = kc & 3;
    size_t dpos = (size_t)c * C_EL + (size_t)st * STRIP_EL
                + (size_t)(ks * 2 + nt) * 512 + (size_t)(lg * 16 + lr) * 8;
    *reinterpret_cast<short8*>(dst + dpos) = cvt8(src + (size_t)idx * 8);
}

__device__ __forceinline__ void gload_lds16(const void* g, void* l) {
    __builtin_amdgcn_global_load_lds(
        (const __attribute__((address_space(1))) unsigned int*)g,
        (__attribute__((address_space(3))) unsigned int*)l, 16, 0, 0);
}

// Grid: (c = 64, bg = 8, which = 2) = 1024 blocks, 256 threads (4 waves).
// Wave w owns batches b0 = bg*8 + w*2 and b0+1 (M = 64 rows).
// D[c] strips staged to LDS (linear, permuted layout), double-buffered.
__global__ __launch_bounds__(256, 4) void maxsim_scores_kernel(
    const __hip_bfloat16* __restrict__ qb,  const __hip_bfloat16* __restrict__ db,
    const __hip_bfloat16* __restrict__ tqb, const __hip_bfloat16* __restrict__ tdb,
    float* __restrict__ scores_ws /* [2][64][64] */) {

    const int c     = blockIdx.x;
    const int bg    = blockIdx.y;
    const int which = blockIdx.z;
    const __hip_bfloat16* Q = which ? tqb : qb;
    const __hip_bfloat16* D = which ? tdb : db;
    float* out = scores_ws + which * (B_SZ * B_SZ);

    const int tid = threadIdx.x;
    const int w   = tid >> 6;     // wave 0..3
    const int l   = tid & 63;     // lane
    const int lg  = l >> 4;       // k-subrange 0..3
    const int lr  = l & 15;       // row/col within 16

    const int b0 = bg * 8 + w * 2;

    __shared__ __align__(16) char smem[2 * STRIP_BYTES];  // 16 KB dbuf

    // A fragments: mt -> batch b0 + (mt>>1), row (mt&1)*16 + lr.
    short8 afrag[4][4];
#pragma unroll
    for (int mt = 0; mt < 4; ++mt)
#pragma unroll
        for (int ks = 0; ks < 4; ++ks)
            afrag[mt][ks] = *reinterpret_cast<const short8*>(
                Q + ((size_t)(b0 + (mt >> 1)) * N_TOK + (mt & 1) * 16 + lr) * D_DIM
                  + ks * 32 + lg * 8);

    float runmax[4][4];
#pragma unroll
    for (int mt = 0; mt < 4; ++mt)
#pragma unroll
        for (int j = 0; j < 4; ++j) runmax[mt][j] = -INFINITY;

    const char* gstrip = (const char*)(D + (size_t)c * C_EL);
    const unsigned y0 = tid * 16;
    const unsigned y1 = 4096 + tid * 16;

    // Prologue: stage strip 0 into buffer 0.
    gload_lds16(gstrip + y0, smem + y0);
    gload_lds16(gstrip + y1, smem + y1);
    __syncthreads();

    for (int st = 0; st < NSTRIP; ++st) {
        const char* bufc = smem + (size_t)(st & 1) * STRIP_BYTES;

        if (st + 1 < NSTRIP) {
            const char* gs = gstrip + (size_t)(st + 1) * STRIP_BYTES;
            char* bufn = smem + (size_t)((st + 1) & 1) * STRIP_BYTES;
            gload_lds16(gs + y0, bufn + y0);
            gload_lds16(gs + y1, bufn + y1);
        }

        // nt-sequential to cap live VGPRs: 4 linear ds_read_b128 + 16 MFMA.
#pragma unroll
        for (int nt = 0; nt < 2; ++nt) {
            short8 bf[4];
#pragma unroll
            for (int ks = 0; ks < 4; ++ks)
                bf[ks] = *reinterpret_cast<const short8*>(
                    bufc + (ks * 2 + nt) * 1024 + l * 16);

            floatx4 acc[4];
#pragma unroll
            for (int mt = 0; mt < 4; ++mt) acc[mt] = floatx4{0.f, 0.f, 0.f, 0.f};

#pragma unroll
            for (int ks = 0; ks < 4; ++ks)
#pragma unroll
                for (int mt = 0; mt < 4; ++mt)
                    acc[mt] = __builtin_amdgcn_mfma_f32_16x16x32_bf16(
                        afrag[mt][ks], bf[ks], acc[mt], 0, 0, 0);

#pragma unroll
            for (int mt = 0; mt < 4; ++mt)
#pragma unroll
                for (int j = 0; j < 4; ++j)
                    runmax[mt][j] = fmaxf(runmax[mt][j], acc[mt][j]);
        }

        __syncthreads();  // dbuf protection (also drains staging)
    }

    // Max over the 16 s-columns spread across lr.
#pragma unroll
    for (int mt = 0; mt < 4; ++mt)
#pragma unroll
        for (int j = 0; j < 4; ++j) {
            float v = runmax[mt][j];
            v = fmaxf(v, __shfl_xor(v, 1));
            v = fmaxf(v, __shfl_xor(v, 2));
            v = fmaxf(v, __shfl_xor(v, 4));
            v = fmaxf(v, __shfl_xor(v, 8));
            runmax[mt][j] = v;
        }

    // Sum rows per batch: batch b0 rows are (mt=0,1, lg*4+j), b0+1 are (mt=2,3).
    float s0 = 0.f, s1 = 0.f;
#pragma unroll
    for (int j = 0; j < 4; ++j) {
        s0 += runmax[0][j] + runmax[1][j];
        s1 += runmax[2][j] + runmax[3][j];
    }
    s0 += __shfl_xor(s0, 16); s0 += __shfl_xor(s0, 32);
    s1 += __shfl_xor(s1, 16); s1 += __shfl_xor(s1, 32);

    if (l == 0) {
        out[b0 * B_SZ + c]       = s0;
        out[(b0 + 1) * B_SZ + c] = s1;
    }
}

// 1 block, 64 threads: final loss.
__global__ void loss_kernel(const float* __restrict__ scores_ws, float* __restrict__ out) {
    const float* sc = scores_ws;                 // student [64][64]
    const float* tc = scores_ws + B_SZ * B_SZ;   // teacher [64][64]
    const int b = threadIdx.x;                   // 0..63

    float pos = sc[b * B_SZ + b];
    float neg = -INFINITY;
    float msesum = 0.f;
#pragma unroll 8
    for (int cc = 0; cc < B_SZ; ++cc) {
        float s = sc[b * B_SZ + cc];
        float t = tc[b * B_SZ + cc];
        if (cc != b) neg = fmaxf(neg, s);
        _Float16 d16 = (_Float16)s - (_Float16)t;  // fp16 subtract (matches ref cast)
        _Float16 sq  = d16 * d16;                  // fp16 square
        msesum += (float)sq;                       // fp32 accumulation
    }
    float x = neg - pos;
    float sp = (x > 0.f) ? (x + log1pf(expf(-x))) : log1pf(expf(x));

#pragma unroll
    for (int m = 1; m < 64; m <<= 1) {
        sp     += __shfl_xor(sp, m);
        msesum += __shfl_xor(msesum, m);
    }
    if (b == 0) {
        float mse = msesum / 4096.f;
        mse = (float)(_Float16)mse;  // jnp.mean returns f16, then astype(f32)
        out[0] = sp / 64.f + ALPHA * mse;
    }
}

extern "C" void kernel_launch(void* const* d_in, const int* in_sizes, int n_in,
                              void* d_out, int out_size, void* d_ws, size_t ws_size,
                              hipStream_t stream) {
    const float* q  = (const float*)d_in[0];
    const float* d  = (const float*)d_in[1];
    const float* tq = (const float*)d_in[2];
    const float* td = (const float*)d_in[3];
    float* out = (float*)d_out;

    const size_t QN = (size_t)B_SZ * N_TOK * D_DIM;   // 262144
    const size_t DN = (size_t)B_SZ * S_TOK * D_DIM;   // 8388608

    float* scores_ws = (float*)d_ws;                                  // 32 KB
    __hip_bfloat16* qb  = (__hip_bfloat16*)((char*)d_ws + 32768);
    __hip_bfloat16* tqb = qb + QN;
    __hip_bfloat16* db  = tqb + QN;
    __hip_bfloat16* tdb = db + DN;

    cvt_q_kernel<<<dim3((unsigned)(QN / 8 / 256), 2), 256, 0, stream>>>(q, tq, qb, tqb);
    cvt_d_kernel<<<dim3((unsigned)(DN / 8 / 256), 2), 256, 0, stream>>>(d, td, db, tdb);

    dim3 grid(B_SZ, B_SZ / 8, 2);
    maxsim_scores_kernel<<<grid, 256, 0, stream>>>(qb, db, tqb, tdb, scores_ws);
    loss_kernel<<<1, 64, 0, stream>>>(scores_ws, out);
}

// Round 5
// 73.979 us; speedup vs baseline: 3.9555x; 1.0836x over previous
//
#include <hip/hip_runtime.h>
#include <hip/hip_bf16.h>

typedef __attribute__((ext_vector_type(8))) short short8;
typedef __attribute__((ext_vector_type(4))) float floatx4;

#define B_SZ   64
#define N_TOK  32
#define S_TOK  1024
#define D_DIM  128
#define ALPHA  0.3f

#define STRIP_S     32
#define STRIP_EL    (STRIP_S * D_DIM)       // 4096 elements
#define STRIP_BYTES (STRIP_EL * 2)          // 8192 B
#define NSTRIP      (S_TOK / STRIP_S)       // 32
#define C_EL        (S_TOK * D_DIM)         // 131072 elements per doc batch

#define DBLK (B_SZ * S_TOK * D_DIM / 8 / 256)   // 4096 blocks for D part
#define QBLK (B_SZ * N_TOK * D_DIM / 8 / 256)   // 128 blocks for Q part

__device__ __forceinline__ short f2bf(float f) {
    __hip_bfloat16 h = __float2bfloat16(f);
    return __builtin_bit_cast(short, h);
}

__device__ __forceinline__ short8 cvt8(const float* __restrict__ p) {
    floatx4 f0 = *reinterpret_cast<const floatx4*>(p);
    floatx4 f1 = *reinterpret_cast<const floatx4*>(p + 4);
    short8 r;
    r[0] = f2bf(f0[0]); r[1] = f2bf(f0[1]); r[2] = f2bf(f0[2]); r[3] = f2bf(f0[3]);
    r[4] = f2bf(f1[0]); r[5] = f2bf(f1[1]); r[6] = f2bf(f1[2]); r[7] = f2bf(f1[3]);
    return r;
}

// One launch converts everything. grid (DBLK + QBLK, 2).
// D part: fp32 -> bf16 with fragment permutation:
//   dst pos = c*C_EL + st*STRIP_EL + (ks*2+nt)*512 + (lg*16+lr)*8
//   where s = st*32 + nt*16 + lr, k = ks*32 + lg*8.
// Q part: plain layout-preserving fp32 -> bf16.
__global__ __launch_bounds__(256) void cvt_all_kernel(
    const float* __restrict__ q,  const float* __restrict__ d,
    const float* __restrict__ tq, const float* __restrict__ td,
    __hip_bfloat16* __restrict__ qb,  __hip_bfloat16* __restrict__ db,
    __hip_bfloat16* __restrict__ tqb, __hip_bfloat16* __restrict__ tdb) {
    const int which = blockIdx.y;
    if (blockIdx.x >= DBLK) {
        const float* src = which ? tq : q;
        __hip_bfloat16* dst = which ? tqb : qb;
        int idx = (blockIdx.x - DBLK) * 256 + threadIdx.x;
        *reinterpret_cast<short8*>(dst + (size_t)idx * 8) = cvt8(src + (size_t)idx * 8);
    } else {
        const float* src = which ? td : d;
        __hip_bfloat16* dst = which ? tdb : db;
        int idx = blockIdx.x * 256 + threadIdx.x;
        int kc = idx & 15;            // k-chunk 0..15
        int s  = (idx >> 4) & (S_TOK - 1);
        int c  = idx >> 14;
        int st = s >> 5, nt = (s >> 4) & 1, lr = s & 15;
        int ks = kc >> 2, lg = kc & 3;
        size_t dpos = (size_t)c * C_EL + (size_t)st * STRIP_EL
                    + (size_t)(ks * 2 + nt) * 512 + (size_t)(lg * 16 + lr) * 8;
        *reinterpret_cast<short8*>(dst + dpos) = cvt8(src + (size_t)idx * 8);
    }
}

__device__ __forceinline__ void gload_lds16(const void* g, void* l) {
    __builtin_amdgcn_global_load_lds(
        (const __attribute__((address_space(1))) unsigned int*)g,
        (__attribute__((address_space(3))) unsigned int*)l, 16, 0, 0);
}

// Grid: (c = 64, bg = 4, which = 2) = 512 blocks (2/CU), 256 threads (4 waves).
// Wave w owns 4 batches b0 = bg*16 + w*4 .. +3 (M = 128 rows per wave).
// D[c] strips staged to LDS (linear, permuted layout), double-buffered.
__global__ __launch_bounds__(256, 2) void maxsim_scores_kernel(
    const __hip_bfloat16* __restrict__ qb,  const __hip_bfloat16* __restrict__ db,
    const __hip_bfloat16* __restrict__ tqb, const __hip_bfloat16* __restrict__ tdb,
    float* __restrict__ scores_ws /* [2][64][64] */) {

    const int c     = blockIdx.x;
    const int bg    = blockIdx.y;
    const int which = blockIdx.z;
    const __hip_bfloat16* Q = which ? tqb : qb;
    const __hip_bfloat16* D = which ? tdb : db;
    float* out = scores_ws + which * (B_SZ * B_SZ);

    const int tid = threadIdx.x;
    const int w   = tid >> 6;     // wave 0..3
    const int l   = tid & 63;     // lane
    const int lg  = l >> 4;       // k-subrange 0..3
    const int lr  = l & 15;       // row/col within 16

    const int b0 = bg * 16 + w * 4;

    __shared__ __align__(16) char smem[2 * STRIP_BYTES];  // 16 KB dbuf

    // A fragments: mt 0..7 -> batch b0 + (mt>>1), row (mt&1)*16 + lr. 128 VGPR.
    short8 afrag[8][4];
#pragma unroll
    for (int mt = 0; mt < 8; ++mt)
#pragma unroll
        for (int ks = 0; ks < 4; ++ks)
            afrag[mt][ks] = *reinterpret_cast<const short8*>(
                Q + ((size_t)(b0 + (mt >> 1)) * N_TOK + (mt & 1) * 16 + lr) * D_DIM
                  + ks * 32 + lg * 8);

    float runmax[8][4];
#pragma unroll
    for (int mt = 0; mt < 8; ++mt)
#pragma unroll
        for (int j = 0; j < 4; ++j) runmax[mt][j] = -INFINITY;

    const char* gstrip = (const char*)(D + (size_t)c * C_EL);
    const unsigned y0 = tid * 16;
    const unsigned y1 = 4096 + tid * 16;

    // Prologue: stage strip 0 into buffer 0.
    gload_lds16(gstrip + y0, smem + y0);
    gload_lds16(gstrip + y1, smem + y1);
    __syncthreads();

    for (int st = 0; st < NSTRIP; ++st) {
        const char* bufc = smem + (size_t)(st & 1) * STRIP_BYTES;

        if (st + 1 < NSTRIP) {
            const char* gs = gstrip + (size_t)(st + 1) * STRIP_BYTES;
            char* bufn = smem + (size_t)((st + 1) & 1) * STRIP_BYTES;
            gload_lds16(gs + y0, bufn + y0);
            gload_lds16(gs + y1, bufn + y1);
        }

        // nt-sequential: per nt, 4 linear ds_read_b128 feed 32 MFMA.
#pragma unroll
        for (int nt = 0; nt < 2; ++nt) {
            short8 bf[4];
#pragma unroll
            for (int ks = 0; ks < 4; ++ks)
                bf[ks] = *reinterpret_cast<const short8*>(
                    bufc + (ks * 2 + nt) * 1024 + l * 16);

            floatx4 acc[8];
#pragma unroll
            for (int mt = 0; mt < 8; ++mt) acc[mt] = floatx4{0.f, 0.f, 0.f, 0.f};

#pragma unroll
            for (int ks = 0; ks < 4; ++ks)
#pragma unroll
                for (int mt = 0; mt < 8; ++mt)
                    acc[mt] = __builtin_amdgcn_mfma_f32_16x16x32_bf16(
                        afrag[mt][ks], bf[ks], acc[mt], 0, 0, 0);

#pragma unroll
            for (int mt = 0; mt < 8; ++mt)
#pragma unroll
                for (int j = 0; j < 4; ++j)
                    runmax[mt][j] = fmaxf(runmax[mt][j], acc[mt][j]);
        }

        __syncthreads();  // dbuf protection (also drains staging)
    }

    // Max over the 16 s-columns spread across lr.
#pragma unroll
    for (int mt = 0; mt < 8; ++mt)
#pragma unroll
        for (int j = 0; j < 4; ++j) {
            float v = runmax[mt][j];
            v = fmaxf(v, __shfl_xor(v, 1));
            v = fmaxf(v, __shfl_xor(v, 2));
            v = fmaxf(v, __shfl_xor(v, 4));
            v = fmaxf(v, __shfl_xor(v, 8));
            runmax[mt][j] = v;
        }

    // Per-batch row sums: batch b0+p covers mt = 2p, 2p+1 (rows lg*4+j).
#pragma unroll
    for (int p = 0; p < 4; ++p) {
        float s = 0.f;
#pragma unroll
        for (int j = 0; j < 4; ++j) s += runmax[2 * p][j] + runmax[2 * p + 1][j];
        s += __shfl_xor(s, 16);
        s += __shfl_xor(s, 32);
        if (l == 0) out[(b0 + p) * B_SZ + c] = s;
    }
}

// 1 block, 64 threads: final loss.
__global__ void loss_kernel(const float* __restrict__ scores_ws, float* __restrict__ out) {
    const float* sc = scores_ws;                 // student [64][64]
    const float* tc = scores_ws + B_SZ * B_SZ;   // teacher [64][64]
    const int b = threadIdx.x;                   // 0..63

    float pos = sc[b * B_SZ + b];
    float neg = -INFINITY;
    float msesum = 0.f;
#pragma unroll 8
    for (int cc = 0; cc < B_SZ; ++cc) {
        float s = sc[b * B_SZ + cc];
        float t = tc[b * B_SZ + cc];
        if (cc != b) neg = fmaxf(neg, s);
        _Float16 d16 = (_Float16)s - (_Float16)t;  // fp16 subtract (matches ref cast)
        _Float16 sq  = d16 * d16;                  // fp16 square
        msesum += (float)sq;                       // fp32 accumulation
    }
    float x = neg - pos;
    float sp = (x > 0.f) ? (x + log1pf(expf(-x))) : log1pf(expf(x));

#pragma unroll
    for (int m = 1; m < 64; m <<= 1) {
        sp     += __shfl_xor(sp, m);
        msesum += __shfl_xor(msesum, m);
    }
    if (b == 0) {
        float mse = msesum / 4096.f;
        mse = (float)(_Float16)mse;  // jnp.mean returns f16, then astype(f32)
        out[0] = sp / 64.f + ALPHA * mse;
    }
}

extern "C" void kernel_launch(void* const* d_in, const int* in_sizes, int n_in,
                              void* d_out, int out_size, void* d_ws, size_t ws_size,
                              hipStream_t stream) {
    const float* q  = (const float*)d_in[0];
    const float* d  = (const float*)d_in[1];
    const float* tq = (const float*)d_in[2];
    const float* td = (const float*)d_in[3];
    float* out = (float*)d_out;

    const size_t QN = (size_t)B_SZ * N_TOK * D_DIM;   // 262144
    const size_t DN = (size_t)B_SZ * S_TOK * D_DIM;   // 8388608

    float* scores_ws = (float*)d_ws;                                  // 32 KB
    __hip_bfloat16* qb  = (__hip_bfloat16*)((char*)d_ws + 32768);
    __hip_bfloat16* tqb = qb + QN;
    __hip_bfloat16* db  = tqb + QN;
    __hip_bfloat16* tdb = db + DN;

    cvt_all_kernel<<<dim3(DBLK + QBLK, 2), 256, 0, stream>>>(
        q, d, tq, td, qb, db, tqb, tdb);

    dim3 grid(B_SZ, B_SZ / 16, 2);
    maxsim_scores_kernel<<<grid, 256, 0, stream>>>(qb, db, tqb, tdb, scores_ws);
    loss_kernel<<<1, 64, 0, stream>>>(scores_ws, out);
}